// Round 4
// baseline (379.134 us; speedup 1.0000x reference)
//
#include <hip/hip_runtime.h>
#include <stdint.h>

#define M_DIM 4096
#define N_DIM 4096
#define K_DIM 4096

#define BM 128
#define BN 128
#define BK 32
#define KT (K_DIM / BK)

typedef __bf16 bf16x8 __attribute__((ext_vector_type(8)));
typedef float f32x16 __attribute__((ext_vector_type(16)));
typedef unsigned short us8 __attribute__((ext_vector_type(8)));

// round-to-nearest-even fp32 -> bf16 bits
__device__ __forceinline__ unsigned short f2bf(float f) {
    unsigned u = __builtin_bit_cast(unsigned, f);
    u = (u + 0x7FFFu + ((u >> 16) & 1u)) >> 16;
    return (unsigned short)u;
}

// ---------------------------------------------------------------- fused prep
// (a) convert 4096 floats of A -> bf16 (same layout); (b) one 64x64 W tile
//     transposed+converted to Wt[n][k]. grid = 4096 blocks.
__global__ __launch_bounds__(256) void prep(const float* __restrict__ A,
                                            unsigned short* __restrict__ Abf,
                                            const float* __restrict__ W,
                                            unsigned short* __restrict__ Wt) {
    const int b = blockIdx.x;
    const int tid = threadIdx.x;

#pragma unroll
    for (int it = 0; it < 4; ++it) {
        const int i = b * 1024 + it * 256 + tid;
        const float4 v = ((const float4*)A)[i];
        ushort4 o;
        o.x = f2bf(v.x);
        o.y = f2bf(v.y);
        o.z = f2bf(v.z);
        o.w = f2bf(v.w);
        ((ushort4*)Abf)[i] = o;
    }

    __shared__ float tile[64][65];
    const int n0 = (b & 63) * 64;
    const int k0 = (b >> 6) * 64;
    const int c = tid & 63;
    const int r4 = tid >> 6;
#pragma unroll
    for (int rr = 0; rr < 16; ++rr) {
        const int row = r4 * 16 + rr;
        tile[row][c] = W[(size_t)(k0 + row) * N_DIM + (n0 + c)];
    }
    __syncthreads();
    const int kc = tid & 7;
#pragma unroll
    for (int half = 0; half < 2; ++half) {
        const int nrow = (tid >> 3) + half * 32;
        us8 o;
#pragma unroll
        for (int i = 0; i < 8; ++i) o[i] = f2bf(tile[kc * 8 + i][nrow]);
        *(us8*)(Wt + (size_t)(n0 + nrow) * K_DIM + k0 + kc * 8) = o;
    }
}

// ---------------------------------------------------------------- GEMM
// m97-family staging (global_load_lds w=16, zero-VALU) + LDS double-buffer
// (one barrier/iter; vmcnt drain covered by ~350 cyc of ds_read+MFMA) +
// 32x32x16 MFMA (2495 TF pipe rate vs 2075 for 16x16x32).
__device__ __forceinline__ void load_lds16(const void* g, void* l) {
    __builtin_amdgcn_global_load_lds(
        (const __attribute__((address_space(1))) void*)g,
        (__attribute__((address_space(3))) void*)l,
        16, 0, 0);
}

__global__ __launch_bounds__(256) void gemm_bf16(const unsigned short* __restrict__ A,
                                                 const unsigned short* __restrict__ Bt,
                                                 const float* __restrict__ bias,
                                                 float* __restrict__ C) {
    __shared__ __align__(16) unsigned short As[2][BM * BK];  // 2 x 8 KB
    __shared__ __align__(16) unsigned short Bs[2][BN * BK];  // 2 x 8 KB

    // XCD-aware supertile swizzle (R2): 8x8 block supertiles per XCD
    const int bid = blockIdx.x;
    const int xcd = bid & 7;
    const int i_ = bid >> 3;
    const int st = xcd + 8 * (i_ >> 6);
    const int within = i_ & 63;
    const int m0 = ((st >> 2) * 8 + (within >> 3)) * BM;
    const int n0 = ((st & 3) * 8 + (within & 7)) * BN;

    const int tid = threadIdx.x;
    const int lane = tid & 63;
    const int wave = tid >> 6;
    const int wm = (wave >> 1) * 64;  // wave tile 64x64 = 2x2 of 32x32
    const int wn = (wave & 1) * 64;
    const int ln31 = lane & 31;
    const int khi = (lane >> 5) * 8;  // A/B frag: k = h*16 + khi + e

    f32x16 acc[2][2] = {};

    // staging map (lane-contiguous, required by global_load_lds):
    // chunk tid: row = tid>>2, 16B k-chunk = tid&3
    const int r0 = tid >> 2;
    const int c0 = tid & 3;
    const unsigned short* agp0 = A + (size_t)(m0 + r0) * K_DIM + c0 * 8;
    const unsigned short* agp1 = agp0 + (size_t)64 * K_DIM;
    const unsigned short* bgp0 = Bt + (size_t)(n0 + r0) * K_DIM + c0 * 8;
    const unsigned short* bgp1 = bgp0 + (size_t)64 * K_DIM;

#define ISSUE(t, buf)                                     \
    do {                                                  \
        load_lds16(agp0 + (t) * BK, As[buf] + tid * 8);   \
        load_lds16(agp1 + (t) * BK, As[buf] + 2048 + tid * 8); \
        load_lds16(bgp0 + (t) * BK, Bs[buf] + tid * 8);   \
        load_lds16(bgp1 + (t) * BK, Bs[buf] + 2048 + tid * 8); \
    } while (0)

    ISSUE(0, 0);
    __syncthreads();  // buf0 ready

    int cur = 0;
    for (int kt = 0; kt < KT; ++kt) {
        if (kt + 1 < KT) ISSUE(kt + 1, cur ^ 1);  // vmcnt in flight across MFMA

        // fragments + MFMA, two k-halves of 16
#pragma unroll
        for (int h = 0; h < 2; ++h) {
            bf16x8 af[2], bf[2];
#pragma unroll
            for (int i = 0; i < 2; ++i)
                af[i] = *(const bf16x8*)(As[cur] + (wm + i * 32 + ln31) * BK + h * 16 + khi);
#pragma unroll
            for (int j = 0; j < 2; ++j)
                bf[j] = *(const bf16x8*)(Bs[cur] + (wn + j * 32 + ln31) * BK + h * 16 + khi);
#pragma unroll
            for (int i = 0; i < 2; ++i)
#pragma unroll
                for (int j = 0; j < 2; ++j)
                    acc[i][j] = __builtin_amdgcn_mfma_f32_32x32x16_bf16(af[i], bf[j], acc[i][j], 0, 0, 0);
        }

        __syncthreads();  // drains t+1 staging + protects buf reuse
        cur ^= 1;
    }
#undef ISSUE

    // 32x32 C/D layout: col = lane&31, row = (reg&3) + 8*(reg>>2) + 4*(lane>>5)
    // [measured m74/m101]
    const int rq = (lane >> 5) * 4;
#pragma unroll
    for (int j = 0; j < 2; ++j) {
        const int col = n0 + wn + j * 32 + ln31;
        const float bj = bias[col];
#pragma unroll
        for (int i = 0; i < 2; ++i) {
            const int mb = m0 + wm + i * 32 + rq;
#pragma unroll
            for (int reg = 0; reg < 16; ++reg) {
                const int row = mb + (reg & 3) + 8 * (reg >> 2);
                C[(size_t)row * N_DIM + col] = acc[i][j][reg] + bj;
            }
        }
    }
}

// ---------------------------------------------------------------- fallback (ws too small)
__global__ __launch_bounds__(256) void naive_gemm(const float* __restrict__ A,
                                                  const float* __restrict__ W,
                                                  const float* __restrict__ bias,
                                                  float* __restrict__ C) {
    const int col = blockIdx.x * 16 + threadIdx.x;
    const int row = blockIdx.y * 16 + threadIdx.y;
    float s = 0.f;
    for (int k = 0; k < K_DIM; ++k)
        s += A[(size_t)row * K_DIM + k] * W[(size_t)k * N_DIM + col];
    C[(size_t)row * N_DIM + col] = s + bias[col];
}

extern "C" void kernel_launch(void* const* d_in, const int* in_sizes, int n_in,
                              void* d_out, int out_size, void* d_ws, size_t ws_size,
                              hipStream_t stream) {
    const float* A = (const float*)d_in[0];
    const float* W = (const float*)d_in[1];
    const float* bias = (const float*)d_in[2];
    float* out = (float*)d_out;

    const size_t need = (size_t)2 * M_DIM * K_DIM * sizeof(unsigned short);  // 67 MB
    if (ws_size >= need) {
        unsigned short* Abf = (unsigned short*)d_ws;
        unsigned short* Wt = Abf + (size_t)M_DIM * K_DIM;
        prep<<<4096, 256, 0, stream>>>(A, Abf, W, Wt);
        gemm_bf16<<<(M_DIM / BM) * (N_DIM / BN), 256, 0, stream>>>(Abf, Wt, bias, out);
    } else {
        naive_gemm<<<dim3(N_DIM / 16, M_DIM / 16), dim3(16, 16), 0, stream>>>(A, W, bias, out);
    }
}

// Round 5
// 332.776 us; speedup vs baseline: 1.1393x; 1.1393x over previous
//
#include <hip/hip_runtime.h>
#include <stdint.h>

#define M_DIM 4096
#define N_DIM 4096
#define K_DIM 4096

#define BM 128
#define BN 128
#define BK 32

typedef __bf16 bf16x8 __attribute__((ext_vector_type(8)));
typedef float f32x4 __attribute__((ext_vector_type(4)));
typedef unsigned short us8 __attribute__((ext_vector_type(8)));

// round-to-nearest-even fp32 -> bf16 bits
__device__ __forceinline__ unsigned short f2bf(float f) {
    unsigned u = __builtin_bit_cast(unsigned, f);
    u = (u + 0x7FFFu + ((u >> 16) & 1u)) >> 16;
    return (unsigned short)u;
}

// ---------------------------------------------------------------- fused prep
// (a) convert 4096 floats of A -> bf16 (same layout); (b) one 64x64 W tile
//     transposed+converted to Wt[n][k]. grid = 4096 blocks.
__global__ __launch_bounds__(256) void prep(const float* __restrict__ A,
                                            unsigned short* __restrict__ Abf,
                                            const float* __restrict__ W,
                                            unsigned short* __restrict__ Wt) {
    const int b = blockIdx.x;
    const int tid = threadIdx.x;

#pragma unroll
    for (int it = 0; it < 4; ++it) {
        const int i = b * 1024 + it * 256 + tid;
        const float4 v = ((const float4*)A)[i];
        ushort4 o;
        o.x = f2bf(v.x);
        o.y = f2bf(v.y);
        o.z = f2bf(v.z);
        o.w = f2bf(v.w);
        ((ushort4*)Abf)[i] = o;
    }

    __shared__ float tile[64][65];
    const int n0 = (b & 63) * 64;
    const int k0 = (b >> 6) * 64;
    const int c = tid & 63;
    const int r4 = tid >> 6;
#pragma unroll
    for (int rr = 0; rr < 16; ++rr) {
        const int row = r4 * 16 + rr;
        tile[row][c] = W[(size_t)(k0 + row) * N_DIM + (n0 + c)];
    }
    __syncthreads();
    const int kc = tid & 7;
#pragma unroll
    for (int half = 0; half < 2; ++half) {
        const int nrow = (tid >> 3) + half * 32;
        us8 o;
#pragma unroll
        for (int i = 0; i < 8; ++i) o[i] = f2bf(tile[kc * 8 + i][nrow]);
        *(us8*)(Wt + (size_t)(n0 + nrow) * K_DIM + k0 + kc * 8) = o;
    }
}

// ---------------------------------------------------------------- GEMM
// R2 structure (m97 recipe: global_load_lds w=16, 2-barrier K-loop) plus
// XOR bank swizzle: LDS 16B-slot s holds global chunk (r=s>>2,
// c=(s&3)^((r>>1)&3)). Fragment reads then spread slot%8 over all 8 bank
// groups per 16-lane phase -> 2-way (free) instead of 8-way conflicts.
__device__ __forceinline__ void load_lds16(const void* g, void* l) {
    __builtin_amdgcn_global_load_lds(
        (const __attribute__((address_space(1))) void*)g,
        (__attribute__((address_space(3))) void*)l,
        16, 0, 0);
}

__global__ __launch_bounds__(256) void gemm_bf16(const unsigned short* __restrict__ A,
                                                 const unsigned short* __restrict__ Bt,
                                                 const float* __restrict__ bias,
                                                 float* __restrict__ C) {
    __shared__ __align__(16) unsigned short As[BM * BK];  // 8 KB, swizzled layout
    __shared__ __align__(16) unsigned short Bs[BN * BK];

    // XCD-aware supertile swizzle (R2): 8x8 block supertiles per XCD
    const int bid = blockIdx.x;
    const int xcd = bid & 7;
    const int i_ = bid >> 3;
    const int st = xcd + 8 * (i_ >> 6);
    const int within = i_ & 63;
    const int m0 = ((st >> 2) * 8 + (within >> 3)) * BM;
    const int n0 = ((st & 3) * 8 + (within & 7)) * BN;

    const int tid = threadIdx.x;
    const int lane = tid & 63;
    const int wave = tid >> 6;
    const int wm = (wave >> 1) * 64;
    const int wn = (wave & 1) * 64;
    const int lrow = lane & 15;
    const int quad = lane >> 4;
    // swizzled k-offset for fragment reads (elements):
    const int kofs = (quad ^ ((lrow >> 1) & 3)) * 8;

    f32x4 acc[4][4] = {};

    // staging: lane tid fills LDS slot tid (and 256+tid); global chunk for
    // slot s: row = s>>2, kchunk = (s&3) ^ ((row>>1)&3). For s=tid and
    // s=256+tid the xor term is ((tid>>3)&3) both times (64 rows = 0 mod 4).
    const int r0 = tid >> 2;
    const int c0 = (tid & 3) ^ ((tid >> 3) & 3);
    const unsigned short* agp0 = A + (size_t)(m0 + r0) * K_DIM + c0 * 8;
    const unsigned short* agp1 = agp0 + (size_t)64 * K_DIM;
    const unsigned short* bgp0 = Bt + (size_t)(n0 + r0) * K_DIM + c0 * 8;
    const unsigned short* bgp1 = bgp0 + (size_t)64 * K_DIM;
    unsigned short* al0 = As + tid * 8;
    unsigned short* al1 = As + (256 + tid) * 8;
    unsigned short* bl0 = Bs + tid * 8;
    unsigned short* bl1 = Bs + (256 + tid) * 8;

    for (int k0 = 0; k0 < K_DIM; k0 += BK) {
        load_lds16(agp0 + k0, al0);
        load_lds16(agp1 + k0, al1);
        load_lds16(bgp0 + k0, bl0);
        load_lds16(bgp1 + k0, bl1);
        __syncthreads();

        bf16x8 af[4], bf[4];
#pragma unroll
        for (int i = 0; i < 4; ++i)
            af[i] = *(const bf16x8*)(As + (wm + i * 16 + lrow) * BK + kofs);
#pragma unroll
        for (int j = 0; j < 4; ++j)
            bf[j] = *(const bf16x8*)(Bs + (wn + j * 16 + lrow) * BK + kofs);
#pragma unroll
        for (int i = 0; i < 4; ++i)
#pragma unroll
            for (int j = 0; j < 4; ++j)
                acc[i][j] = __builtin_amdgcn_mfma_f32_16x16x32_bf16(af[i], bf[j], acc[i][j], 0, 0, 0);
        __syncthreads();
    }

    // C/D layout: col = lane&15, row = quad*4 + reg   [measured m89/m91]
#pragma unroll
    for (int j = 0; j < 4; ++j) {
        const int col = n0 + wn + j * 16 + lrow;
        const float bj = bias[col];
#pragma unroll
        for (int i = 0; i < 4; ++i) {
            const int rbase = m0 + wm + i * 16 + quad * 4;
#pragma unroll
            for (int r = 0; r < 4; ++r)
                C[(size_t)(rbase + r) * N_DIM + col] = acc[i][j][r] + bj;
        }
    }
}

// ---------------------------------------------------------------- fallback (ws too small)
__global__ __launch_bounds__(256) void naive_gemm(const float* __restrict__ A,
                                                  const float* __restrict__ W,
                                                  const float* __restrict__ bias,
                                                  float* __restrict__ C) {
    const int col = blockIdx.x * 16 + threadIdx.x;
    const int row = blockIdx.y * 16 + threadIdx.y;
    float s = 0.f;
    for (int k = 0; k < K_DIM; ++k)
        s += A[(size_t)row * K_DIM + k] * W[(size_t)k * N_DIM + col];
    C[(size_t)row * N_DIM + col] = s + bias[col];
}

extern "C" void kernel_launch(void* const* d_in, const int* in_sizes, int n_in,
                              void* d_out, int out_size, void* d_ws, size_t ws_size,
                              hipStream_t stream) {
    const float* A = (const float*)d_in[0];
    const float* W = (const float*)d_in[1];
    const float* bias = (const float*)d_in[2];
    float* out = (float*)d_out;

    const size_t need = (size_t)2 * M_DIM * K_DIM * sizeof(unsigned short);  // 67 MB
    if (ws_size >= need) {
        unsigned short* Abf = (unsigned short*)d_ws;
        unsigned short* Wt = Abf + (size_t)M_DIM * K_DIM;
        prep<<<4096, 256, 0, stream>>>(A, Abf, W, Wt);
        gemm_bf16<<<(M_DIM / BM) * (N_DIM / BN), 256, 0, stream>>>(Abf, Wt, bias, out);
    } else {
        naive_gemm<<<dim3(N_DIM / 16, M_DIM / 16), dim3(16, 16), 0, stream>>>(A, W, bias, out);
    }
}